// Round 1
// baseline (88.005 us; speedup 1.0000x reference)
//
#include <hip/hip_runtime.h>
#include <hip/hip_bf16.h>

#define NN 4096
#define CC 25
#define GPC 80
#define HH 8
#define SS 32
#define GG 2000   // CC * GPC

// Kernel 1: one block per sample. Computes pre-BN output row (32 floats) into ws.
__global__ __launch_bounds__(256) void k_forward(
    const int*   __restrict__ x,          // [N, G]
    const float* __restrict__ emb,        // [G, 3, H]
    const float* __restrict__ gene_att,   // [C, H]
    const float* __restrict__ chrom_att,  // [H]
    const float* __restrict__ W,          // [H, S]
    const float* __restrict__ b,          // [S]
    float*       __restrict__ raw)        // [N, S] pre-BN
{
    __shared__ int   xrow[GG];       // 8000 B
    __shared__ float ce[CC][HH];     // 800 B  (relu'd chrom_emb)

    const int n    = blockIdx.x;
    const int tid  = threadIdx.x;
    const int wave = tid >> 6;
    const int lane = tid & 63;

    // Stage this sample's x row into LDS, fully coalesced.
    for (int i = tid; i < GG; i += 256) xrow[i] = x[(size_t)n * GG + i];
    __syncthreads();

    // Each wave handles chroms c = wave, wave+4, ...
    for (int c = wave; c < CC; c += 4) {
        float ga[HH];
        #pragma unroll
        for (int h = 0; h < HH; ++h) ga[h] = gene_att[c * HH + h];

        float asum = 0.f;
        float acc[HH];
        #pragma unroll
        for (int h = 0; h < HH; ++h) acc[h] = 0.f;

        #pragma unroll
        for (int rep = 0; rep < 2; ++rep) {
            int gg = lane + rep * 64;
            if (gg < GPC) {
                int g  = c * GPC + gg;
                int xv = xrow[g];
                const float* e = emb + ((size_t)g * 3 + xv) * HH;
                float4 e0 = *(const float4*)(e);
                float4 e1 = *(const float4*)(e + 4);
                float ev[HH] = {e0.x, e0.y, e0.z, e0.w, e1.x, e1.y, e1.z, e1.w};

                float logit = 0.f;
                #pragma unroll
                for (int h = 0; h < HH; ++h) logit += ga[h] * ev[h];

                // reference: m = (att != 0); att = exp(leaky_relu(att)) * m
                float att = 0.f;
                if (logit != 0.f) {
                    float lr = (logit >= 0.f) ? logit : 0.01f * logit;
                    att = expf(lr);
                }
                asum += att;
                #pragma unroll
                for (int h = 0; h < HH; ++h) acc[h] += att * ev[h];
            }
        }

        // 64-lane butterfly reduction of asum + acc[8]
        #pragma unroll
        for (int off = 32; off >= 1; off >>= 1) {
            asum += __shfl_xor(asum, off, 64);
            #pragma unroll
            for (int h = 0; h < HH; ++h) acc[h] += __shfl_xor(acc[h], off, 64);
        }

        if (lane == 0) {
            float inv = 1.f / asum;   // chrom_emb = (Σ att·h) / Σ att, then relu
            #pragma unroll
            for (int h = 0; h < HH; ++h) {
                float v = acc[h] * inv;
                ce[c][h] = (v > 0.f) ? v : 0.f;
            }
        }
    }
    __syncthreads();

    // Second attention + GEMV: wave 0 only.
    if (wave == 0) {
        float a = 0.f;
        float cev[HH];
        if (lane < CC) {
            #pragma unroll
            for (int h = 0; h < HH; ++h) cev[h] = ce[lane][h];
            float d = 0.f;
            #pragma unroll
            for (int h = 0; h < HH; ++h) d += chrom_att[h] * cev[h];
            float lr = (d >= 0.f) ? d : 0.01f * d;
            a = expf(lr);   // no mask on second stage (matches reference)
        } else {
            #pragma unroll
            for (int h = 0; h < HH; ++h) cev[h] = 0.f;
        }

        float asum = a;
        #pragma unroll
        for (int off = 32; off >= 1; off >>= 1) asum += __shfl_xor(asum, off, 64);
        float an = a / asum;

        float sig[HH];
        #pragma unroll
        for (int h = 0; h < HH; ++h) sig[h] = an * cev[h];
        #pragma unroll
        for (int off = 32; off >= 1; off >>= 1) {
            #pragma unroll
            for (int h = 0; h < HH; ++h) sig[h] += __shfl_xor(sig[h], off, 64);
        }
        #pragma unroll
        for (int h = 0; h < HH; ++h) sig[h] = (sig[h] > 0.f) ? sig[h] : 0.f;

        if (lane < SS) {
            float o = b[lane];
            #pragma unroll
            for (int h = 0; h < HH; ++h) o += sig[h] * W[h * SS + lane];
            raw[(size_t)n * SS + lane] = o;
        }
    }
}

// Kernel 2: batch-norm over N. One block per output column s — deterministic tree.
__global__ __launch_bounds__(256) void k_bn(
    const float* __restrict__ raw, float* __restrict__ out)
{
    const int s   = blockIdx.x;
    const int tid = threadIdx.x;
    const int wave = tid >> 6;
    const int lane = tid & 63;

    float sum = 0.f, sq = 0.f;
    for (int n = tid; n < NN; n += 256) {
        float v = raw[(size_t)n * SS + s];
        sum += v; sq += v * v;
    }
    #pragma unroll
    for (int off = 32; off >= 1; off >>= 1) {
        sum += __shfl_xor(sum, off, 64);
        sq  += __shfl_xor(sq,  off, 64);
    }

    __shared__ float wsum[4], wsq[4];
    __shared__ float s_mu, s_inv;
    if (lane == 0) { wsum[wave] = sum; wsq[wave] = sq; }
    __syncthreads();
    if (tid == 0) {
        float ts = 0.f, tq = 0.f;
        for (int w = 0; w < 4; ++w) { ts += wsum[w]; tq += wsq[w]; }
        float mu  = ts / (float)NN;
        float var = tq / (float)NN - mu * mu;
        s_mu  = mu;
        s_inv = rsqrtf(var + 1e-5f);
    }
    __syncthreads();
    const float mu = s_mu, inv = s_inv;
    for (int n = tid; n < NN; n += 256) {
        out[(size_t)n * SS + s] = (raw[(size_t)n * SS + s] - mu) * inv;
    }
}

extern "C" void kernel_launch(void* const* d_in, const int* in_sizes, int n_in,
                              void* d_out, int out_size, void* d_ws, size_t ws_size,
                              hipStream_t stream) {
    const int*   x         = (const int*)  d_in[0];
    const float* emb       = (const float*)d_in[1];
    // d_in[2] = chrom_mask: block-diagonal by construction — structure exploited, unused.
    const float* gene_att  = (const float*)d_in[3];
    const float* chrom_att = (const float*)d_in[4];
    const float* W         = (const float*)d_in[5];
    const float* b         = (const float*)d_in[6];
    float* out = (float*)d_out;
    float* raw = (float*)d_ws;   // N*S floats = 512 KB

    k_forward<<<NN, 256, 0, stream>>>(x, emb, gene_att, chrom_att, W, b, raw);
    k_bn<<<SS, 256, 0, stream>>>(raw, out);
}

// Round 2
// 56.489 us; speedup vs baseline: 1.5579x; 1.5579x over previous
//
#include <hip/hip_runtime.h>
#include <hip/hip_bf16.h>

#define NN   4096
#define CC   25
#define GPCg 80
#define HH   8
#define SS   32
#define GG   2000
#define NSUB 5                       // chrom subsets
#define CSUB 5                       // chroms per subset
#define GSUB (CSUB*GPCg)             // 400 genes per subset
#define TSTR 11                      // floats per table row (9 used + 2 pad; 33 dwords/gene ≡ 1 mod 32 -> conflict-free)
#define TROWS (GG*3)                 // 6000
#define SLICE_FLOATS (GSUB*3*TSTR)   // 13200 floats = 52.8 KB

// ws layout (floats)
#define WS_T    0                    // 6000*11 = 66000 -> pad to 66048
#define WS_CE   66048                // 4096*200 = 819200
#define WS_RAW  (WS_CE + 819200)     // 4096*32 = 131072
#define WS_PART (WS_RAW + 131072)    // 512*32*2 = 32768 (float2)
#define WS_MS   (WS_PART + 32768)    // 32*2

// ---------------------------------------------------------------------------
// Kernel A: precompute T[g][xv] = {att, att*ev[0..7]} for all 6000 (g,xv).
__global__ __launch_bounds__(256) void k_table(
    const float* __restrict__ emb, const float* __restrict__ gene_att,
    float* __restrict__ T)
{
    int idx = blockIdx.x * 256 + threadIdx.x;
    if (idx >= TROWS) return;
    int g = idx / 3, xv = idx - g * 3;
    int c = g / GPCg;
    const float* e = emb + ((size_t)g * 3 + xv) * HH;
    float4 e0 = *(const float4*)(e);
    float4 e1 = *(const float4*)(e + 4);
    float ev[HH] = {e0.x, e0.y, e0.z, e0.w, e1.x, e1.y, e1.z, e1.w};
    float logit = 0.f;
    #pragma unroll
    for (int h = 0; h < HH; ++h) logit += gene_att[c * HH + h] * ev[h];
    float att = 0.f;
    if (logit != 0.f) {
        float lr = (logit >= 0.f) ? logit : 0.01f * logit;
        att = expf(lr);
    }
    float* row = T + (size_t)idx * TSTR;
    row[0] = att;
    #pragma unroll
    for (int h = 0; h < HH; ++h) row[1 + h] = att * ev[h];
}

// ---------------------------------------------------------------------------
// Kernel B: main. Block = (chrom subset k, 16 samples). Table slice in LDS.
// Wave-iteration: 4 samples x 1 chrom; 16 lanes/sample, 5 genes/lane (t, t+16,..).
__global__ __launch_bounds__(256) void k_main(
    const int* __restrict__ x, const float* __restrict__ T,
    float* __restrict__ ce)
{
    __shared__ float Ts[SLICE_FLOATS];

    const int bid = blockIdx.x;           // 1280 = (4096/16) * 5
    const int k   = bid % NSUB;
    const int n0  = (bid / NSUB) * 16;

    {   // stage table slice, coalesced float4
        const float4* src = (const float4*)(T + (size_t)k * SLICE_FLOATS);
        float4* dst = (float4*)Ts;
        #pragma unroll 2
        for (int i = threadIdx.x; i < SLICE_FLOATS / 4; i += 256) dst[i] = src[i];
    }
    __syncthreads();

    const int wave = threadIdx.x >> 6;
    const int lane = threadIdx.x & 63;
    const int q = lane >> 4;              // sample within quad
    const int t = lane & 15;              // lane within group

    for (int u = wave; u < CSUB * 4; u += 4) {
        const int cl = u >> 2;            // chrom within subset
        const int qd = u & 3;             // sample-quad
        const int n  = n0 + qd * 4 + q;
        const int* xp = x + (size_t)n * GG + k * GSUB + cl * GPCg;

        float asum = 0.f;
        float acc[HH] = {0.f, 0.f, 0.f, 0.f, 0.f, 0.f, 0.f, 0.f};

        #pragma unroll
        for (int j = 0; j < 5; ++j) {
            const int gl = j * 16 + t;               // gene within chrom
            const int xv = xp[gl];                   // coalesced across lanes
            const float* r = Ts + ((cl * GPCg + gl) * 3 + xv) * TSTR;
            asum += r[0];
            #pragma unroll
            for (int h = 0; h < HH; ++h) acc[h] += r[1 + h];
        }

        #pragma unroll
        for (int off = 8; off >= 1; off >>= 1) {
            asum += __shfl_xor(asum, off);
            #pragma unroll
            for (int h = 0; h < HH; ++h) acc[h] += __shfl_xor(acc[h], off);
        }

        if (t < HH) {
            const float inv = 1.f / asum;
            float v = acc[0];
            #pragma unroll
            for (int h = 1; h < HH; ++h) if (t == h) v = acc[h];  // static-indexed select
            v *= inv;
            v = (v > 0.f) ? v : 0.f;
            ce[(size_t)n * (CC * HH) + (k * CSUB + cl) * HH + t] = v;
        }
    }
}

// ---------------------------------------------------------------------------
// Kernel C: second attention + GEMV + BN partial sums. Half-wave per sample.
__global__ __launch_bounds__(256) void k_second(
    const float* __restrict__ ce, const float* __restrict__ chrom_att,
    const float* __restrict__ W, const float* __restrict__ b,
    float* __restrict__ raw, float2* __restrict__ part)
{
    const int tid  = threadIdx.x;
    const int half = tid >> 5;            // 8 samples per block
    const int j    = tid & 31;
    const int n    = blockIdx.x * 8 + half;

    float cev[HH];
    float a = 0.f;
    if (j < CC) {
        const float4* p = (const float4*)(ce + (size_t)n * (CC * HH) + j * HH);
        float4 v0 = p[0], v1 = p[1];
        cev[0]=v0.x; cev[1]=v0.y; cev[2]=v0.z; cev[3]=v0.w;
        cev[4]=v1.x; cev[5]=v1.y; cev[6]=v1.z; cev[7]=v1.w;
        float d = 0.f;
        #pragma unroll
        for (int h = 0; h < HH; ++h) d += chrom_att[h] * cev[h];
        float lr = (d >= 0.f) ? d : 0.01f * d;
        a = expf(lr);
    } else {
        #pragma unroll
        for (int h = 0; h < HH; ++h) cev[h] = 0.f;
    }

    float asum = a;
    #pragma unroll
    for (int off = 16; off >= 1; off >>= 1) asum += __shfl_xor(asum, off, 32);
    const float an = a / asum;

    float sig[HH];
    #pragma unroll
    for (int h = 0; h < HH; ++h) sig[h] = an * cev[h];
    #pragma unroll
    for (int off = 16; off >= 1; off >>= 1) {
        #pragma unroll
        for (int h = 0; h < HH; ++h) sig[h] += __shfl_xor(sig[h], off, 32);
    }
    #pragma unroll
    for (int h = 0; h < HH; ++h) sig[h] = fmaxf(sig[h], 0.f);

    float o = b[j];
    #pragma unroll
    for (int h = 0; h < HH; ++h) o += sig[h] * W[h * SS + j];
    raw[(size_t)n * SS + j] = o;

    // BN partials: reduce the block's 8 samples per column
    __shared__ float psum[8][SS], psq[8][SS];
    psum[half][j] = o;
    psq[half][j]  = o * o;
    __syncthreads();
    if (tid < SS) {
        float s1 = 0.f, s2 = 0.f;
        #pragma unroll
        for (int r = 0; r < 8; ++r) { s1 += psum[r][tid]; s2 += psq[r][tid]; }
        part[(size_t)blockIdx.x * SS + tid] = make_float2(s1, s2);
    }
}

// ---------------------------------------------------------------------------
// Kernel D: reduce 512 partials -> mu, inv_sigma per column.
__global__ __launch_bounds__(256) void k_bn_stats(
    const float2* __restrict__ part, float2* __restrict__ musig)
{
    const int tid = threadIdx.x;
    const int s = tid & 31, r = tid >> 5;
    float s1 = 0.f, s2 = 0.f;
    for (int bb = r; bb < 512; bb += 8) {
        float2 p = part[(size_t)bb * SS + s];
        s1 += p.x; s2 += p.y;
    }
    __shared__ float a1[8][SS], a2[8][SS];
    a1[r][s] = s1; a2[r][s] = s2;
    __syncthreads();
    if (tid < SS) {
        float t1 = 0.f, t2 = 0.f;
        #pragma unroll
        for (int rr = 0; rr < 8; ++rr) { t1 += a1[rr][tid]; t2 += a2[rr][tid]; }
        float mu  = t1 / (float)NN;
        float var = t2 / (float)NN - mu * mu;
        musig[tid] = make_float2(mu, rsqrtf(var + 1e-5f));
    }
}

// ---------------------------------------------------------------------------
// Kernel E: normalize, fully coalesced float4.
__global__ __launch_bounds__(256) void k_bn_norm(
    const float* __restrict__ raw, const float2* __restrict__ musig,
    float* __restrict__ out)
{
    __shared__ float2 ms[SS];
    if (threadIdx.x < SS) ms[threadIdx.x] = musig[threadIdx.x];
    __syncthreads();
    const int i = blockIdx.x * 256 + threadIdx.x;   // over 32768 float4
    float4 v = ((const float4*)raw)[i];
    const int s0 = (i * 4) & 31;
    float4 o;
    o.x = (v.x - ms[s0+0].x) * ms[s0+0].y;
    o.y = (v.y - ms[s0+1].x) * ms[s0+1].y;
    o.z = (v.z - ms[s0+2].x) * ms[s0+2].y;
    o.w = (v.w - ms[s0+3].x) * ms[s0+3].y;
    ((float4*)out)[i] = o;
}

// ---------------------------------------------------------------------------
extern "C" void kernel_launch(void* const* d_in, const int* in_sizes, int n_in,
                              void* d_out, int out_size, void* d_ws, size_t ws_size,
                              hipStream_t stream) {
    const int*   x         = (const int*)  d_in[0];
    const float* emb       = (const float*)d_in[1];
    // d_in[2] = chrom_mask: block-diagonal by construction — exploited, unused.
    const float* gene_att  = (const float*)d_in[3];
    const float* chrom_att = (const float*)d_in[4];
    const float* W         = (const float*)d_in[5];
    const float* b         = (const float*)d_in[6];
    float* out = (float*)d_out;

    float*  fws   = (float*)d_ws;
    float*  T     = fws + WS_T;
    float*  ce    = fws + WS_CE;
    float*  raw   = fws + WS_RAW;
    float2* part  = (float2*)(fws + WS_PART);
    float2* musig = (float2*)(fws + WS_MS);

    k_table  <<<(TROWS + 255) / 256, 256, 0, stream>>>(emb, gene_att, T);
    k_main   <<<(NN / 16) * NSUB,    256, 0, stream>>>(x, T, ce);
    k_second <<<NN / 8,              256, 0, stream>>>(ce, chrom_att, W, b, raw, part);
    k_bn_stats<<<1,                  256, 0, stream>>>(part, musig);
    k_bn_norm<<<(NN * SS / 4) / 256, 256, 0, stream>>>(raw, musig, out);
}